// Round 8
// baseline (3637.323 us; speedup 1.0000x reference)
//
#include <hip/hip_runtime.h>
#include <math.h>

#define NC1 150
#define HW 196          // 14*14
#define NB 1024
#define DD 32
#define NHD 4
#define HDIM 8
#define KG 2352         // ceil(0.08 * 150*14*14)
#define KCH 10

#define CVST 51         // cand_v row stride (floats): odd -> conflict-light
#define CCST 52         // cand_c row stride (bytes)
#define UBUFN 12544     // floats: cand_v 196*51=9996 + cand_c 196*52B=2548 floats

// ---------------- K0: 2D sinusoidal positional embedding [196,32] ----------------
__global__ void pos2d_kernel(float* __restrict__ pos) {
  int i = blockIdx.x * 256 + threadIdx.x;
  if (i >= HW * DD) return;
  int s = i >> 5, d = i & 31;
  int h = s / 14, w = s % 14;
  int p = (d < 16) ? h : w;
  int dd = (d < 16) ? d : d - 16;
  int j = dd >> 1;
  float dv = expf(-(logf(10000.0f) / 16.0f) * (float)(2 * j));
  float ang = (float)p * dv;
  pos[i] = (dd & 1) ? cosf(ang) : sinf(ang);
}

// extract window elements [K0,K1) of the 84-slot (9x9 + 3 pad) patch
template<int K0, int K1>
__device__ __forceinline__ void extract_win(const float* __restrict__ xs, int h, int w,
                                            float* __restrict__ xr) {
#pragma unroll
  for (int k = K0; k < K1; ++k) {
    if (k < 81) {
      int i = k / 9, j = k % 9;
      int r = 2 * h - 4 + i, cl = 2 * w - 4 + j;
      xr[k - K0] = (r >= 0 && r < 28 && cl >= 0 && cl < 28) ? xs[r * 28 + cl] : 0.f;
    } else {
      xr[k - K0] = 0.f;
    }
  }
}

// accumulate NCH channels over weight quads [KQ0,KQ1); xr holds elems 4*KQ0..4*KQ1
template<int NCH, int KQ0, int KQ1>
__device__ __forceinline__ void conv_acc(const float* __restrict__ wp,
                                         const float* __restrict__ xr,
                                         float* __restrict__ acc) {
#pragma unroll
  for (int pr = 0; pr < NCH / 2; ++pr) {
    const float* w0 = wp + (2 * pr + 0) * 84;
    const float* w1 = wp + (2 * pr + 1) * 84;
#pragma unroll
    for (int kq = KQ0; kq < KQ1; ++kq) {
      float4 a0 = *(const float4*)(w0 + kq * 4);
      float4 a1 = *(const float4*)(w1 + kq * 4);
      int kb = (kq - KQ0) * 4;
      acc[2 * pr + 0] += xr[kb + 0] * a0.x;
      acc[2 * pr + 0] += xr[kb + 1] * a0.y;
      acc[2 * pr + 0] += xr[kb + 2] * a0.z;
      acc[2 * pr + 0] += xr[kb + 3] * a0.w;
      acc[2 * pr + 1] += xr[kb + 0] * a1.x;
      acc[2 * pr + 1] += xr[kb + 1] * a1.y;
      acc[2 * pr + 1] += xr[kb + 2] * a1.z;
      acc[2 * pr + 1] += xr[kb + 3] * a1.w;
    }
  }
}

// ---------------- K1 (fused): conv -> register radix kth -> strip-top10 merge ------
// R8: no As[196x153] LDS array. Conv values stay in registers (30 ch/thread);
// per-location top-10 = merge of 5 per-strip top-10s (superset proof: any element of
// the location's top-10 is in its strip's top-10; thresholded zeros are scatter
// no-ops). LDS ~62 KB -> 2 blocks/CU. amdgpu_waves_per_eu(4,4) pins the register
// plan to 4 waves/EU (128 VGPR) so a_r[30]+xw[28]+acc[16] fits without scratch.
__global__ __launch_bounds__(1024) __attribute__((amdgpu_waves_per_eu(4, 4)))
void fused_kernel(const float* __restrict__ x,
                  const float* __restrict__ cw,
                  const float* __restrict__ CE,
                  const float* __restrict__ pos,
                  float* __restrict__ seqo) {
  __shared__ alignas(16) float ubuf[UBUFN];   // 50176 B: wl | cand | CEs (phased)
  __shared__ alignas(16) float xs[784];       // 3136 B
  __shared__ unsigned hist[2048];             // 8192 B
  __shared__ unsigned wsum[4];
  __shared__ unsigned s_prefix, s_krem, s_max;   // total ~61.6 KB -> 2 blocks/CU

  int b = blockIdx.x, tid = threadIdx.x;
  int lane = tid & 63, wid = tid >> 6;

  if (tid < 196) ((float4*)xs)[tid] = ((const float4*)(x + (size_t)b * 784))[tid];
  if (tid == 0) { s_prefix = 0u; s_krem = KG; s_max = 0u; }
  __syncthreads();

  int strip = tid / 196;            // 0..4 active
  int s = tid - strip * 196;
  bool act = (tid < 980);
  int h = s / 14, w = s % 14;

  float a_r[30];
#pragma unroll
  for (int q = 0; q < 30; ++q) a_r[q] = 0.f;

  float* wl = ubuf;
  // ---- conv phase 0: channels [0,80), strip owns 16 ----
  for (int i = tid; i < 80 * 84; i += 1024) {
    int rr = i / 84, k = i - rr * 84;
    wl[i] = (k < 81) ? cw[rr * 81 + k] : 0.f;
  }
  __syncthreads();
  if (act) {
    const float* wp = wl + strip * 16 * 84;
    float acc[16];
#pragma unroll
    for (int q = 0; q < 16; ++q) acc[q] = 0.f;
    { float xw[28]; extract_win<0, 28>(xs, h, w, xw);  conv_acc<16, 0, 7>(wp, xw, acc); }
    { float xw[28]; extract_win<28, 56>(xs, h, w, xw); conv_acc<16, 7, 14>(wp, xw, acc); }
    { float xw[28]; extract_win<56, 84>(xs, h, w, xw); conv_acc<16, 14, 21>(wp, xw, acc); }
#pragma unroll
    for (int q = 0; q < 16; ++q) a_r[q] = fmaxf(acc[q], 0.f);
  }
  __syncthreads();                  // ph0 wl reads done
  // ---- conv phase 1: channels [80,150), strip owns 14 ----
  for (int i = tid; i < 70 * 84; i += 1024) {
    int rr = i / 84, k = i - rr * 84;
    wl[i] = (k < 81) ? cw[(80 + rr) * 81 + k] : 0.f;
  }
  __syncthreads();
  if (act) {
    const float* wp = wl + strip * 14 * 84;
    float acc[14];
#pragma unroll
    for (int q = 0; q < 14; ++q) acc[q] = 0.f;
    { float xw[28]; extract_win<0, 28>(xs, h, w, xw);  conv_acc<14, 0, 7>(wp, xw, acc); }
    { float xw[28]; extract_win<28, 56>(xs, h, w, xw); conv_acc<14, 7, 14>(wp, xw, acc); }
    { float xw[28]; extract_win<56, 84>(xs, h, w, xw); conv_acc<14, 14, 21>(wp, xw, acc); }
#pragma unroll
    for (int q = 0; q < 14; ++q) a_r[16 + q] = fmaxf(acc[q], 0.f);
  }
  __syncthreads();                  // ph1 wl reads done; ubuf free for candidates

  // ---- per-strip top-10 (raw values, stable ascending channel) -> LDS cand ----
  float* cand_v = ubuf;                                   // [196][51] floats
  unsigned char* cand_c = (unsigned char*)(ubuf + 9996);  // [196][52] bytes
  if (act) {
    float tv[KCH]; int tc[KCH];
#pragma unroll
    for (int k = 0; k < KCH; ++k) { tv[k] = -1.0f; tc[k] = 0; }
#pragma unroll
    for (int q = 0; q < 30; ++q) {
      int c = (q < 16) ? (strip * 16 + q) : (80 + strip * 14 + (q - 16));
      float iv = a_r[q]; int ic = c;
      if (iv > tv[KCH - 1]) {
#pragma unroll
        for (int j = 0; j < KCH; ++j) {
          bool gt = iv > tv[j];
          float nv = gt ? iv : tv[j]; int nc = gt ? ic : tc[j];
          float ov = gt ? tv[j] : iv; int oc = gt ? tc[j] : ic;
          tv[j] = nv; tc[j] = nc; iv = ov; ic = oc;
        }
      }
    }
#pragma unroll
    for (int k = 0; k < KCH; ++k) {
      cand_v[s * CVST + strip * 10 + k] = tv[k];
      cand_c[s * CCST + strip * 10 + k] = (unsigned char)tc[k];
    }
  }
  // ---- per-sample max: registers -> wave shfl -> 1 atomic/wave ----
  {
    float vm = 0.f;
#pragma unroll
    for (int q = 0; q < 30; ++q) vm = fmaxf(vm, a_r[q]);
    unsigned um = __float_as_uint(vm);   // non-neg: bit order == float order
#pragma unroll
    for (int off = 32; off >= 1; off >>= 1) um = max(um, (unsigned)__shfl_xor((int)um, off));
    if (lane == 0) atomicMax(&s_max, um);
  }

  // ---- kth: 3-pass radix select from REGISTERS (zero-skip exact; R7-verified) ----
  for (int pass = 0; pass < 3; ++pass) {
    hist[tid] = 0u; hist[tid + 1024] = 0u;
    __syncthreads();
    int shift = (pass == 0) ? 21 : (pass == 1 ? 10 : 0);
    int bits = (pass == 2) ? 10 : 11;
    unsigned mask = (1u << bits) - 1u;
    unsigned pfx = s_prefix;          // snapshot after barrier; written pre-barrier
    unsigned krem = s_krem;
    int hishift = shift + bits;
    if (pass == 0) {
#pragma unroll
      for (int q = 0; q < 30; ++q) {
        unsigned u = __float_as_uint(a_r[q]);
        if (u) atomicAdd(&hist[u >> 21], 1u);
      }
    } else {
#pragma unroll
      for (int q = 0; q < 30; ++q) {
        unsigned u = __float_as_uint(a_r[q]);
        if (u && (u >> hishift) == pfx) atomicAdd(&hist[(u >> shift) & mask], 1u);
      }
    }
    __syncthreads();
    int segsz = (1 << bits) >> 8;     // 8 or 4
    unsigned segv = 0u, sufv = 0u;
    if (tid < 256) {
      for (int j = 0; j < segsz; ++j) segv += hist[tid * segsz + j];
      sufv = segv;
#pragma unroll
      for (int st = 1; st < 64; st <<= 1) {
        unsigned o = (unsigned)__shfl_down((int)sufv, st);
        if (lane + st < 64) sufv += o;
      }
      if (lane == 0) wsum[wid] = sufv;
    }
    __syncthreads();
    if (tid < 256) {
      unsigned tail = 0u;
      for (int ww = wid + 1; ww < 4; ++ww) tail += wsum[ww];
      sufv += tail;                      // count in segments >= tid
      unsigned above = sufv - segv;
      if (above < krem && sufv >= krem) {   // unique winner
        unsigned cum = above;
        int dsel = tid * segsz;
        for (int d2 = segsz - 1; d2 >= 0; --d2) {
          int dd = tid * segsz + d2;
          if (cum + hist[dd] >= krem) { dsel = dd; break; }
          cum += hist[dd];
        }
        s_prefix = (pfx << bits) | (unsigned)dsel;
        s_krem = krem - cum;
      }
    }
    __syncthreads();
  }

  // ---- merge 50 candidates -> location top-10 (thresholded, stable) ----
  float T = __uint_as_float(s_prefix);
  float gm = __uint_as_float(s_max);
  float gi = (gm == 0.0f) ? 0.0f : 1.0f / gm;
  float tv[KCH]; int tc[KCH];
  if (tid < 196) {
#pragma unroll
    for (int k = 0; k < KCH; ++k) { tv[k] = -1.0f; tc[k] = 0; }
    for (int j = 0; j < 50; ++j) {
      float v = cand_v[tid * CVST + j];
      int c = cand_c[tid * CCST + j];
      v = (v >= T) ? v : 0.0f;          // sentinel -1 -> 0; zeros are no-ops later
      if (v > tv[KCH - 1]) {
        float iv = v; int ic = c;
#pragma unroll
        for (int k = 0; k < KCH; ++k) {
          bool gt = iv > tv[k];
          float nv = gt ? iv : tv[k]; int nc = gt ? ic : tc[k];
          float ov = gt ? tv[k] : iv; int oc = gt ? tc[k] : ic;
          tv[k] = nv; tc[k] = nc; iv = ov; ic = oc;
        }
      }
    }
  }
  __syncthreads();                  // cand reads done; ubuf free for CE
  // ---- stage CE [150][33] ----
  float* CEs = ubuf;
  for (int i = tid; i < NC1 * 32; i += 1024) {
    int c = i >> 5, e = i & 31;
    CEs[c * 33 + e] = CE[i];
  }
  __syncthreads();
  // ---- embed + PE -> seq ----
  if (tid < 196) {
    float acc[32];
#pragma unroll
    for (int e = 0; e < 32; ++e) acc[e] = 0.f;
#pragma unroll
    for (int k = 0; k < KCH; ++k) {   // tv[k] >= 0 always (post-threshold)
      float v = tv[k];
      const float* cr = CEs + tc[k] * 33;
#pragma unroll
      for (int e = 0; e < 32; ++e) acc[e] += v * cr[e];
    }
    float* op = seqo + ((size_t)b * HW + tid) * DD;
    const float* pr = pos + tid * DD;
#pragma unroll
    for (int e4 = 0; e4 < 8; ++e4) {
      float4 pv = ((const float4*)pr)[e4];
      float4 o;
      o.x = acc[e4 * 4 + 0] * gi + pv.x;
      o.y = acc[e4 * 4 + 1] * gi + pv.y;
      o.z = acc[e4 * 4 + 2] * gi + pv.z;
      o.w = acc[e4 * 4 + 3] * gi + pv.w;
      ((float4*)op)[e4] = o;
    }
  }
}

// ---------------- K4: one-layer MHA, single-pass softmax w/ Cauchy-Schwarz shift ----
__global__ __launch_bounds__(256) void attn_kernel(const float* __restrict__ seq,
                                                   const float* __restrict__ Wqkv,
                                                   const float* __restrict__ bqkv,
                                                   float* __restrict__ ctxo) {
  __shared__ float sq[HW * HDIM], sk[HW * HDIM], sv[HW * HDIM];
  __shared__ float swq[24 * DD];
  __shared__ float sbq[24];
  __shared__ unsigned s_kk;
  int blk = blockIdx.x;
  int b = blk >> 2, h = blk & 3;
  int tid = threadIdx.x;
  for (int i = tid; i < 24 * DD; i += 256) {
    int r = i >> 5, e = i & 31;
    int grow = (r >> 3) * DD + h * HDIM + (r & 7);
    swq[i] = Wqkv[grow * DD + e];
  }
  if (tid < 24) sbq[tid] = bqkv[(tid >> 3) * DD + h * HDIM + (tid & 7)];
  if (tid == 0) s_kk = 0u;
  __syncthreads();
  if (tid < HW) {
    int s = tid;
    const float* row = seq + ((size_t)b * HW + s) * DD;
    float xr[32];
#pragma unroll
    for (int e = 0; e < 8; ++e) {
      float4 f = ((const float4*)row)[e];
      xr[e * 4 + 0] = f.x; xr[e * 4 + 1] = f.y; xr[e * 4 + 2] = f.z; xr[e * 4 + 3] = f.w;
    }
    float kk = 0.f;
#pragma unroll
    for (int r = 0; r < 24; ++r) {
      const float* wr = swq + r * DD;
      float acc = sbq[r];
#pragma unroll
      for (int e = 0; e < DD; e += 4) {
        float4 wv = *(const float4*)(wr + e);
        acc += xr[e + 0] * wv.x + xr[e + 1] * wv.y + xr[e + 2] * wv.z + xr[e + 3] * wv.w;
      }
      int which = r >> 3, d = r & 7;
      if (which == 0) sq[s * HDIM + d] = acc;
      else if (which == 1) { sk[s * HDIM + d] = acc; kk += acc * acc; }
      else sv[s * HDIM + d] = acc;
    }
    atomicMax(&s_kk, __float_as_uint(kk));
  }
  __syncthreads();
  if (tid >= HW) return;
  int qr = tid;
  float qreg[HDIM];
  float qq = 0.f;
#pragma unroll
  for (int d = 0; d < HDIM; ++d) { qreg[d] = sq[qr * HDIM + d]; qq += qreg[d] * qreg[d]; }
  const float scale = 0.3535533905932738f;
  float kkmax = __uint_as_float(s_kk);
  float negM = -sqrtf(qq * kkmax) * scale;
  float l = 0.f, ctx[HDIM];
#pragma unroll
  for (int d = 0; d < HDIM; ++d) ctx[d] = 0.f;
#pragma unroll 2
  for (int t = 0; t < HW; ++t) {
    const float* kr = sk + t * HDIM;
    float sc = 0.f;
#pragma unroll
    for (int d = 0; d < HDIM; ++d) sc += qreg[d] * kr[d];
    float p = __expf(fmaf(sc, scale, negM));
    l += p;
    const float* vr = sv + t * HDIM;
#pragma unroll
    for (int d = 0; d < HDIM; ++d) ctx[d] += p * vr[d];
  }
  float inv = 1.0f / l;
  float* op = ctxo + ((size_t)b * HW + qr) * DD + h * HDIM;
  float4 o0, o1;
  o0.x = ctx[0] * inv; o0.y = ctx[1] * inv; o0.z = ctx[2] * inv; o0.w = ctx[3] * inv;
  o1.x = ctx[4] * inv; o1.y = ctx[5] * inv; o1.z = ctx[6] * inv; o1.w = ctx[7] * inv;
  ((float4*)op)[0] = o0; ((float4*)op)[1] = o1;
}

// ---------------- K5: out projection, 1 thread per row (no redundant ctx reads) ----
__global__ __launch_bounds__(256) void outproj_kernel(const float* __restrict__ ctx,
                                                      const float* __restrict__ Wo,
                                                      const float* __restrict__ bo,
                                                      float* __restrict__ out) {
  __shared__ float sw[32 * 32];
  __shared__ float sb2[32];
  int tid = threadIdx.x;
  for (int i = tid; i < 1024; i += 256) sw[i] = Wo[i];
  if (tid < 32) sb2[tid] = bo[tid];
  __syncthreads();
  size_t row = (size_t)blockIdx.x * 256 + tid;   // grid 784 x 256 == 200704 exact
  const float* cr = ctx + row * 32;
  float xr[32];
#pragma unroll
  for (int e = 0; e < 8; ++e) {
    float4 f = ((const float4*)cr)[e];
    xr[e * 4 + 0] = f.x; xr[e * 4 + 1] = f.y; xr[e * 4 + 2] = f.z; xr[e * 4 + 3] = f.w;
  }
  float* op = out + row * 32;
#pragma unroll
  for (int d4 = 0; d4 < 8; ++d4) {
    float4 o;
    float* oo = (float*)&o;
#pragma unroll
    for (int q = 0; q < 4; ++q) {
      int d = d4 * 4 + q;
      float acc = sb2[d];
      const float* wr = sw + d * 32;
#pragma unroll
      for (int e = 0; e < 32; e += 4) {
        float4 wv = *(const float4*)(wr + e);
        acc += xr[e + 0] * wv.x + xr[e + 1] * wv.y + xr[e + 2] * wv.z + xr[e + 3] * wv.w;
      }
      oo[q] = acc;
    }
    ((float4*)op)[d4] = o;
  }
}

extern "C" void kernel_launch(void* const* d_in, const int* in_sizes, int n_in,
                              void* d_out, int out_size, void* d_ws, size_t ws_size,
                              hipStream_t stream) {
  const float* x  = (const float*)d_in[0];
  const float* cw = (const float*)d_in[1];
  const float* ce = (const float*)d_in[2];
  const float* wq = (const float*)d_in[3];
  const float* bq = (const float*)d_in[4];
  const float* wo = (const float*)d_in[5];
  const float* bo = (const float*)d_in[6];
  float* out = (float*)d_out;
  float* ws  = (float*)d_ws;

  // ws layout (floats): ctx [NB*HW*DD] | pos [196*32]
  float* ctx = ws;
  float* pos = ws + (size_t)NB * HW * DD;

  pos2d_kernel<<<(HW * DD + 255) / 256, 256, 0, stream>>>(pos);
  fused_kernel<<<NB, 1024, 0, stream>>>(x, cw, ce, pos, out);   // seq -> d_out
  attn_kernel<<<NB * NHD, 256, 0, stream>>>(out, wq, bq, ctx);  // ctx -> ws
  outproj_kernel<<<(NB * HW * DD) / (256 * 32), 256, 0, stream>>>(ctx, wo, bo, out);
}

// Round 9
// 561.694 us; speedup vs baseline: 6.4756x; 6.4756x over previous
//
#include <hip/hip_runtime.h>
#include <math.h>

#define NC1 150
#define HW 196          // 14*14
#define CST 153         // As row stride: odd -> conflict-free scalar ds access
#define NTOTF (HW*CST)  // 29988 (divisible by 4)
#define NB 1024
#define DD 32
#define NHD 4
#define HDIM 8
#define KG 2352         // ceil(0.08 * 150*14*14)
#define KCH 10

#define XT_OFF 0        // X^T [21][196] floats
#define WT_OFF 4116     // W^T [21][152] floats
#define UNIONF 7308     // union floats (CE[150][33]=4950 overlays later)

// ---------------- K0: 2D sinusoidal positional embedding [196,32] ----------------
__global__ void pos2d_kernel(float* __restrict__ pos) {
  int i = blockIdx.x * 256 + threadIdx.x;
  if (i >= HW * DD) return;
  int s = i >> 5, d = i & 31;
  int h = s / 14, w = s % 14;
  int p = (d < 16) ? h : w;
  int dd = (d < 16) ? d : d - 16;
  int j = dd >> 1;
  float dv = expf(-(logf(10000.0f) / 16.0f) * (float)(2 * j));
  float ang = (float)p * dv;
  pos[i] = (dd & 1) ? cosf(ang) : sinf(ang);
}

// ---------------- K1 (fused): im2col-GEMM conv -> LDS radix kth -> top10+embed ----
// R9: R6 skeleton (As in LDS, LDS radix sweeps, full-row seq scan — all proven)
// with conv restructured as GEMM: per k-phase stage X^T[21][196] (per-lane distinct
// b128 reads, full bank utilization) and W^T[21][152] (broadcast), thread tile
// 4 locs x 8 ch -> 3 LDS instr per 32 FMAs (was 2 per 8 -> 120k cyc of broadcast
// pressure in R6). __launch_bounds__(1024,4) caps VGPR at 128 (R7/R8 spilled at 64).
__global__ __launch_bounds__(1024, 4) void fused_kernel(const float* __restrict__ x,
                                                        const float* __restrict__ cw,
                                                        const float* __restrict__ CE,
                                                        const float* __restrict__ pos,
                                                        float* __restrict__ seqo) {
  __shared__ alignas(16) float As[NTOTF];     // 119952 B
  __shared__ alignas(16) float ubuf[UNIONF];  // 29232 B: XT|WT, later CE[150][33]
  __shared__ alignas(16) float xs[784];       // 3136 B
  __shared__ unsigned hist[2048];             // 8192 B
  __shared__ unsigned wsum[4];
  __shared__ unsigned s_prefix, s_krem, s_max;   // total ~160.5 KB

  int b = blockIdx.x, tid = threadIdx.x;
  int lane = tid & 63, wid = tid >> 6;

  if (tid < 196) ((float4*)xs)[tid] = ((const float4*)(x + (size_t)b * 784))[tid];
  if (tid == 0) { s_prefix = 0u; s_krem = KG; s_max = 0u; }
  __syncthreads();

  int cg = tid / 49;              // ch-group 0..18 (8 ch each, 152 incl 2 pad)
  int g  = tid - cg * 49;         // loc-group 0..48 (4 locs each, 196 exact)
  bool act = (tid < 931);         // 19*49
  float acc[4][8];
#pragma unroll
  for (int i = 0; i < 4; ++i)
#pragma unroll
    for (int j = 0; j < 8; ++j) acc[i][j] = 0.f;

  float* XT = ubuf + XT_OFF;      // [21][196]
  float* WT = ubuf + WT_OFF;      // [21][152]

  for (int kb = 0; kb < 84; kb += 21) {
    __syncthreads();              // previous-phase XT/WT readers done
    // build X^T[kk][s] = x-window element k=kb+kk at location s (0 if OOB/pad)
    for (int i = tid; i < 21 * 196; i += 1024) {
      int kk = i / 196, s = i - kk * 196;
      int k = kb + kk;
      float v = 0.f;
      if (k < 81) {
        int ki = k / 9, kj = k - ki * 9;
        int h = s / 14, w = s - h * 14;
        int r = 2 * h - 4 + ki, c = 2 * w - 4 + kj;
        if (r >= 0 && r < 28 && c >= 0 && c < 28) v = xs[r * 28 + c];
      }
      XT[i] = v;
    }
    // build W^T[kk][c] (c>=150 or k>=81 -> 0)
    for (int i = tid; i < 21 * 152; i += 1024) {
      int kk = i / 152, c = i - kk * 152;
      int k = kb + kk;
      WT[i] = (k < 81 && c < NC1) ? cw[c * 81 + k] : 0.f;
    }
    __syncthreads();
    if (act) {
      const float* xtp = XT + 4 * g;
      const float* wtp = WT + 8 * cg;
#pragma unroll 7
      for (int kk = 0; kk < 21; ++kk) {
        float4 xv = *(const float4*)(xtp + kk * 196);
        float4 w0 = *(const float4*)(wtp + kk * 152);
        float4 w1 = *(const float4*)(wtp + kk * 152 + 4);
        float xa[4] = {xv.x, xv.y, xv.z, xv.w};
        float wa[8] = {w0.x, w0.y, w0.z, w0.w, w1.x, w1.y, w1.z, w1.w};
#pragma unroll
        for (int i = 0; i < 4; ++i)
#pragma unroll
          for (int j = 0; j < 8; ++j) acc[i][j] += xa[i] * wa[j];
      }
    }
  }
  __syncthreads();                // last-phase reads done
  // ---- ReLU + write As (scalar ds_write, stride 153 = conflict-free) ----
  if (act) {
#pragma unroll
    for (int i = 0; i < 4; ++i) {
      float* dst = As + (4 * g + i) * CST + 8 * cg;
#pragma unroll
      for (int j = 0; j < 8; ++j) dst[j] = fmaxf(acc[i][j], 0.f);
    }
  }
  if (tid < 196) As[tid * CST + 152] = 0.f;   // ch 150/151 zeroed via WT pad
  __syncthreads();

  // ---- stage CE into dead ubuf (padded to 33/row) ----
  float* CEs = ubuf;
  for (int i = tid; i < NC1 * 32; i += 1024) {
    int c = i >> 5, e = i & 31;
    CEs[c * 33 + e] = CE[i];
  }

  // ---- kth: 3-pass radix select, LDS float4 sweeps (R6-proven), zero-skip ----
  unsigned mymax = 0u;
  __syncthreads();
  const float4* Ab = (const float4*)As;
  for (int pass = 0; pass < 3; ++pass) {
    hist[tid] = 0u; hist[tid + 1024] = 0u;
    __syncthreads();
    int shift = (pass == 0) ? 21 : (pass == 1 ? 10 : 0);
    int bits = (pass == 2) ? 10 : 11;
    unsigned mask = (1u << bits) - 1u;
    unsigned pfx = s_prefix;        // snapshot after barrier
    unsigned krem = s_krem;
    int hishift = shift + bits;
    for (int i = tid; i < NTOTF / 4; i += 1024) {
      float4 f = Ab[i];
      unsigned u0 = __float_as_uint(f.x), u1 = __float_as_uint(f.y);
      unsigned u2 = __float_as_uint(f.z), u3 = __float_as_uint(f.w);
      if (pass == 0) {
        mymax = max(mymax, max(max(u0, u1), max(u2, u3)));
        if (u0) atomicAdd(&hist[u0 >> 21], 1u);
        if (u1) atomicAdd(&hist[u1 >> 21], 1u);
        if (u2) atomicAdd(&hist[u2 >> 21], 1u);
        if (u3) atomicAdd(&hist[u3 >> 21], 1u);
      } else {
        if (u0 && (u0 >> hishift) == pfx) atomicAdd(&hist[(u0 >> shift) & mask], 1u);
        if (u1 && (u1 >> hishift) == pfx) atomicAdd(&hist[(u1 >> shift) & mask], 1u);
        if (u2 && (u2 >> hishift) == pfx) atomicAdd(&hist[(u2 >> shift) & mask], 1u);
        if (u3 && (u3 >> hishift) == pfx) atomicAdd(&hist[(u3 >> shift) & mask], 1u);
      }
    }
    if (pass == 0) atomicMax(&s_max, mymax);
    __syncthreads();
    int segsz = (1 << bits) >> 8;   // 8 or 4
    unsigned segv = 0u, sufv = 0u;
    if (tid < 256) {
      for (int j = 0; j < segsz; ++j) segv += hist[tid * segsz + j];
      sufv = segv;
#pragma unroll
      for (int st = 1; st < 64; st <<= 1) {
        unsigned o = (unsigned)__shfl_down((int)sufv, st);
        if (lane + st < 64) sufv += o;
      }
      if (lane == 0) wsum[wid] = sufv;
    }
    __syncthreads();
    if (tid < 256) {
      unsigned tail = 0u;
      for (int ww = wid + 1; ww < 4; ++ww) tail += wsum[ww];
      sufv += tail;                    // count in segments >= tid
      unsigned above = sufv - segv;
      if (above < krem && sufv >= krem) {   // unique winner
        unsigned cum = above;
        int dsel = tid * segsz;
        for (int d2 = segsz - 1; d2 >= 0; --d2) {
          int dd = tid * segsz + d2;
          if (cum + hist[dd] >= krem) { dsel = dd; break; }
          cum += hist[dd];
        }
        s_prefix = (pfx << bits) | (unsigned)dsel;
        s_krem = krem - cum;
      }
    }
    __syncthreads();
  }

  // ---- seq: thread-per-location streaming top-10 + CE embed + PE (R6-proven) ----
  float T = __uint_as_float(s_prefix);
  float gm = __uint_as_float(s_max);
  float gi = (gm == 0.0f) ? 0.0f : 1.0f / gm;
  if (tid < 196) {
    const float* row = As + tid * CST;
    float tv[KCH]; int tc[KCH];
#pragma unroll
    for (int k = 0; k < KCH; ++k) { tv[k] = -1.0f; tc[k] = 0; }
    for (int c = 0; c < NC1; ++c) {
      float v = row[c];
      v = (v >= T) ? v : 0.0f;
      if (v > tv[KCH - 1]) {            // stable: earlier c wins ties
        float iv = v; int ic = c;
#pragma unroll
        for (int j = 0; j < KCH; ++j) {
          bool gt = iv > tv[j];
          float nv = gt ? iv : tv[j]; int nc = gt ? ic : tc[j];
          float ov = gt ? tv[j] : iv; int oc = gt ? tc[j] : ic;
          tv[j] = nv; tc[j] = nc; iv = ov; ic = oc;
        }
      }
    }
    float acc2[32];
#pragma unroll
    for (int e = 0; e < 32; ++e) acc2[e] = 0.f;
#pragma unroll
    for (int k = 0; k < KCH; ++k) {     // tv >= 0 post-threshold; zeros are no-ops
      float v = tv[k];
      const float* cr = CEs + tc[k] * 33;
#pragma unroll
      for (int e = 0; e < 32; ++e) acc2[e] += v * cr[e];
    }
    float* op = seqo + ((size_t)b * HW + tid) * DD;
    const float* pr = pos + tid * DD;
#pragma unroll
    for (int e4 = 0; e4 < 8; ++e4) {
      float4 pv = ((const float4*)pr)[e4];
      float4 o;
      o.x = acc2[e4 * 4 + 0] * gi + pv.x;
      o.y = acc2[e4 * 4 + 1] * gi + pv.y;
      o.z = acc2[e4 * 4 + 2] * gi + pv.z;
      o.w = acc2[e4 * 4 + 3] * gi + pv.w;
      ((float4*)op)[e4] = o;
    }
  }
}

// ---------------- K4: one-layer MHA, single-pass softmax w/ Cauchy-Schwarz shift ----
__global__ __launch_bounds__(256) void attn_kernel(const float* __restrict__ seq,
                                                   const float* __restrict__ Wqkv,
                                                   const float* __restrict__ bqkv,
                                                   float* __restrict__ ctxo) {
  __shared__ float sq[HW * HDIM], sk[HW * HDIM], sv[HW * HDIM];
  __shared__ float swq[24 * DD];
  __shared__ float sbq[24];
  __shared__ unsigned s_kk;
  int blk = blockIdx.x;
  int b = blk >> 2, h = blk & 3;
  int tid = threadIdx.x;
  for (int i = tid; i < 24 * DD; i += 256) {
    int r = i >> 5, e = i & 31;
    int grow = (r >> 3) * DD + h * HDIM + (r & 7);
    swq[i] = Wqkv[grow * DD + e];
  }
  if (tid < 24) sbq[tid] = bqkv[(tid >> 3) * DD + h * HDIM + (tid & 7)];
  if (tid == 0) s_kk = 0u;
  __syncthreads();
  if (tid < HW) {
    int s = tid;
    const float* row = seq + ((size_t)b * HW + s) * DD;
    float xr[32];
#pragma unroll
    for (int e = 0; e < 8; ++e) {
      float4 f = ((const float4*)row)[e];
      xr[e * 4 + 0] = f.x; xr[e * 4 + 1] = f.y; xr[e * 4 + 2] = f.z; xr[e * 4 + 3] = f.w;
    }
    float kk = 0.f;
#pragma unroll
    for (int r = 0; r < 24; ++r) {
      const float* wr = swq + r * DD;
      float acc = sbq[r];
#pragma unroll
      for (int e = 0; e < DD; e += 4) {
        float4 wv = *(const float4*)(wr + e);
        acc += xr[e + 0] * wv.x + xr[e + 1] * wv.y + xr[e + 2] * wv.z + xr[e + 3] * wv.w;
      }
      int which = r >> 3, d = r & 7;
      if (which == 0) sq[s * HDIM + d] = acc;
      else if (which == 1) { sk[s * HDIM + d] = acc; kk += acc * acc; }
      else sv[s * HDIM + d] = acc;
    }
    atomicMax(&s_kk, __float_as_uint(kk));
  }
  __syncthreads();
  if (tid >= HW) return;
  int qr = tid;
  float qreg[HDIM];
  float qq = 0.f;
#pragma unroll
  for (int d = 0; d < HDIM; ++d) { qreg[d] = sq[qr * HDIM + d]; qq += qreg[d] * qreg[d]; }
  const float scale = 0.3535533905932738f;
  float kkmax = __uint_as_float(s_kk);
  float negM = -sqrtf(qq * kkmax) * scale;
  float l = 0.f, ctx[HDIM];
#pragma unroll
  for (int d = 0; d < HDIM; ++d) ctx[d] = 0.f;
#pragma unroll 2
  for (int t = 0; t < HW; ++t) {
    const float* kr = sk + t * HDIM;
    float sc = 0.f;
#pragma unroll
    for (int d = 0; d < HDIM; ++d) sc += qreg[d] * kr[d];
    float p = __expf(fmaf(sc, scale, negM));
    l += p;
    const float* vr = sv + t * HDIM;
#pragma unroll
    for (int d = 0; d < HDIM; ++d) ctx[d] += p * vr[d];
  }
  float inv = 1.0f / l;
  float* op = ctxo + ((size_t)b * HW + qr) * DD + h * HDIM;
  float4 o0, o1;
  o0.x = ctx[0] * inv; o0.y = ctx[1] * inv; o0.z = ctx[2] * inv; o0.w = ctx[3] * inv;
  o1.x = ctx[4] * inv; o1.y = ctx[5] * inv; o1.z = ctx[6] * inv; o1.w = ctx[7] * inv;
  ((float4*)op)[0] = o0; ((float4*)op)[1] = o1;
}

// ---------------- K5: out projection, 1 thread per row ----------------
__global__ __launch_bounds__(256) void outproj_kernel(const float* __restrict__ ctx,
                                                      const float* __restrict__ Wo,
                                                      const float* __restrict__ bo,
                                                      float* __restrict__ out) {
  __shared__ float sw[32 * 32];
  __shared__ float sb2[32];
  int tid = threadIdx.x;
  for (int i = tid; i < 1024; i += 256) sw[i] = Wo[i];
  if (tid < 32) sb2[tid] = bo[tid];
  __syncthreads();
  size_t row = (size_t)blockIdx.x * 256 + tid;   // grid covers 200704 exactly
  const float* cr = ctx + row * 32;
  float xr[32];
#pragma unroll
  for (int e = 0; e < 8; ++e) {
    float4 f = ((const float4*)cr)[e];
    xr[e * 4 + 0] = f.x; xr[e * 4 + 1] = f.y; xr[e * 4 + 2] = f.z; xr[e * 4 + 3] = f.w;
  }
  float* op = out + row * 32;
#pragma unroll
  for (int d4 = 0; d4 < 8; ++d4) {
    float4 o;
    float* oo = (float*)&o;
#pragma unroll
    for (int q = 0; q < 4; ++q) {
      int d = d4 * 4 + q;
      float acc = sb2[d];
      const float* wr = sw + d * 32;
#pragma unroll
      for (int e = 0; e < 32; e += 4) {
        float4 wv = *(const float4*)(wr + e);
        acc += xr[e + 0] * wv.x + xr[e + 1] * wv.y + xr[e + 2] * wv.z + xr[e + 3] * wv.w;
      }
      oo[q] = acc;
    }
    ((float4*)op)[d4] = o;
  }
}

extern "C" void kernel_launch(void* const* d_in, const int* in_sizes, int n_in,
                              void* d_out, int out_size, void* d_ws, size_t ws_size,
                              hipStream_t stream) {
  const float* x  = (const float*)d_in[0];
  const float* cw = (const float*)d_in[1];
  const float* ce = (const float*)d_in[2];
  const float* wq = (const float*)d_in[3];
  const float* bq = (const float*)d_in[4];
  const float* wo = (const float*)d_in[5];
  const float* bo = (const float*)d_in[6];
  float* out = (float*)d_out;
  float* ws  = (float*)d_ws;

  // ws layout (floats): ctx [NB*HW*DD] | pos [196*32]
  float* ctx = ws;
  float* pos = ws + (size_t)NB * HW * DD;

  pos2d_kernel<<<(HW * DD + 255) / 256, 256, 0, stream>>>(pos);
  fused_kernel<<<NB, 1024, 0, stream>>>(x, cw, ce, pos, out);   // seq -> d_out
  attn_kernel<<<NB * NHD, 256, 0, stream>>>(out, wq, bq, ctx);  // ctx -> ws
  outproj_kernel<<<(NB * HW * DD) / (256 * 32), 256, 0, stream>>>(ctx, wo, bo, out);
}